// Round 5
// baseline (217.151 us; speedup 1.0000x reference)
//
#include <hip/hip_runtime.h>
#include <hip/hip_bf16.h>
#include <hip/hip_fp16.h>

// out[e] = relu(z_s[row[e]]@W1_top + z_c[col[e]]@W1_bot + b1) @ W2 + b2
// u_s = z_s@W1_top + b1 (f16), u_c = z_c@W1_bot (f16) in ws.
// Edges counting-sorted by row>>8 (391 buckets, 256 rows = 64KB f16 window).
// Edge kernel: one WG per bucket, stages its u_s window into LDS (XOR-swizzled),
// reads only u_c (256B/edge) from cache. 4 launches:
//   K1 conv+partial-hist | K2 scan | K3 scatter||gemm | K4 edge.

typedef _Float16 half2v __attribute__((ext_vector_type(2)));
typedef _Float16 half8v __attribute__((ext_vector_type(8)));
typedef __fp16   fp16x2 __attribute__((ext_vector_type(2)));
typedef float    float4v __attribute__((ext_vector_type(4)));

#define NB 512          // bins (buckets 0..390 used)
#define EBLK_H 8192     // edges per hist block
#define EBLK_S 2048     // edges per scatter block

// ---- K1: blocks 0-7 transpose W1->Wt f16; block 8 W2->f16; blocks 9+ partial hist ----
__global__ __launch_bounds__(256) void k1_conv_hist(
    const float* __restrict__ W1, const float* __restrict__ W2,
    const int* __restrict__ row,
    _Float16* __restrict__ Wt, _Float16* __restrict__ w2h,
    unsigned* __restrict__ part, int E)
{
    int b = blockIdx.x, t = threadIdx.x;
    if (b >= 9) {                       // partial histogram, plain stores (no init needed)
        __shared__ unsigned h[NB];
        h[t] = 0; h[t + 256] = 0;
        __syncthreads();
        int hb = b - 9;
        long b0 = (long)hb * EBLK_H;
        for (int i = 0; i < 32; ++i) {
            long e = b0 + i * 256 + t;
            if (e < E) atomicAdd(&h[row[e] >> 8], 1u);
        }
        __syncthreads();
        part[hb * NB + t] = h[t];
        part[hb * NB + t + 256] = h[t + 256];
        return;
    }
    if (b == 8) { if (t < 128) w2h[t] = (_Float16)W2[t]; return; }
    __shared__ _Float16 lds[32][136];
    int h2 = b >> 2, n0 = (b & 3) * 32;
    for (int i = 0; i < 16; ++i) {
        int idx = i * 256 + t;          // 4096 = 128k x 32n
        int k = idx >> 5, nn = idx & 31;
        lds[nn][k] = (_Float16)W1[(h2 * 128 + k) * 128 + n0 + nn];
    }
    __syncthreads();
    for (int j = 0; j < 2; ++j) {
        int idx = j * 256 + t;          // 512 = 32n x 16 chunks
        int nn = idx >> 4, kc = idx & 15;
        half8v v;
        #pragma unroll
        for (int q = 0; q < 8; ++q) v[q] = lds[nn][kc * 8 + q];
        *(half8v*)&Wt[((h2 * 128 + n0 + nn) * 128) + kc * 8] = v;
    }
}

// ---- K2: reduce partial hists + exclusive scan -> bucketStart, cursor ----
__global__ __launch_bounds__(512) void k2_scan(const unsigned* __restrict__ part,
                                               unsigned* __restrict__ bucketStart,
                                               unsigned* __restrict__ cursor,
                                               int nbh, int E)
{
    __shared__ unsigned s[NB];
    int t = threadIdx.x;
    unsigned v = 0;
    for (int b = 0; b < nbh; ++b) v += part[b * NB + t];
    s[t] = v;
    __syncthreads();
    for (int d = 1; d < NB; d <<= 1) {
        unsigned x = (t >= d) ? s[t - d] : 0u;
        __syncthreads();
        s[t] += x;
        __syncthreads();
    }
    unsigned excl = s[t] - v;
    bucketStart[t] = excl;              // bins >= nbuckets are 0 -> bucketStart[b+1]=E works
    cursor[t] = excl;
    if (t == 0) bucketStart[NB] = (unsigned)E;
}

// ---- K3: blocks [0,nbs_s) scatter edges; rest = fused GEMM ----
__global__ __launch_bounds__(256) void k3_scatter_gemm(
    const int* __restrict__ row, const int* __restrict__ col,
    unsigned* __restrict__ cursor, uint2* __restrict__ perm, int E, int nbs_s,
    const float* __restrict__ Zs, const float* __restrict__ Zc,
    const _Float16* __restrict__ Wt, const float* __restrict__ b1,
    _Float16* __restrict__ Us, _Float16* __restrict__ Uc,
    int Ms, int Mc, int nbs)
{
    const int t = threadIdx.x;
    if (blockIdx.x < (unsigned)nbs_s) {
        // ---------------- scatter ----------------
        __shared__ unsigned h[NB];
        __shared__ unsigned base[NB];
        h[t] = 0; h[t + 256] = 0;
        __syncthreads();
        long b0 = (long)blockIdx.x * EBLK_S;
        int sk[8], rr[8], cc[8];
        #pragma unroll
        for (int i = 0; i < 8; ++i) {
            long e = b0 + i * 256 + t;
            if (e < E) {
                rr[i] = row[e]; cc[i] = col[e];
                sk[i] = rr[i] >> 8;
                atomicAdd(&h[sk[i]], 1u);
            } else sk[i] = -1;
        }
        __syncthreads();
        if (h[t]) base[t] = atomicAdd(&cursor[t], h[t]);
        if (h[t + 256]) base[t + 256] = atomicAdd(&cursor[t + 256], h[t + 256]);
        __syncthreads();
        h[t] = 0; h[t + 256] = 0;
        __syncthreads();
        #pragma unroll
        for (int i = 0; i < 8; ++i) {
            if (sk[i] >= 0) {
                unsigned off = atomicAdd(&h[sk[i]], 1u);
                unsigned pos = base[sk[i]] + off;
                long e = b0 + i * 256 + t;
                perm[pos] = make_uint2(((unsigned)(rr[i] & 255) << 15) | (unsigned)cc[i],
                                       (unsigned)e);
            }
        }
        return;
    }
    // ---------------- GEMM ----------------
    __shared__ uint4 ldsW[2048];        // 128 rows x 16 chunks, swizzled
    const int bid = blockIdx.x - nbs_s;

    const float* Z; _Float16* U; const _Float16* W; int M, m0, addB;
    if (bid < nbs) { Z = Zs; U = Us; M = Ms; m0 = bid * 64;         W = Wt;         addB = 1; }
    else           { Z = Zc; U = Uc; M = Mc; m0 = (bid - nbs) * 64; W = Wt + 16384; addB = 0; }

    const uint4* Wv = (const uint4*)W;
    #pragma unroll
    for (int i = 0; i < 8; ++i) {
        int j = i * 256 + t;
        int n = j >> 4, ch = j & 15;
        ldsW[n * 16 + (ch ^ ((n >> 3) & 7))] = Wv[j];
    }
    __syncthreads();

    const int wave = t >> 6, lane = t & 63, quad = lane >> 4, l16 = lane & 15;
    int mrow = m0 + wave * 16 + l16;
    int mload = mrow < M ? mrow : M - 1;
    const float* zrow = Z + (long)mload * 128;

    float4v acc[8];
    #pragma unroll
    for (int nt = 0; nt < 8; ++nt) acc[nt] = (float4v)(0.0f);

    #pragma unroll
    for (int c = 0; c < 4; ++c) {
        const float4v* pa = (const float4v*)(zrow + c * 32 + quad * 8);
        float4v a0 = pa[0], a1 = pa[1];
        fp16x2 p[4];
        p[0] = __builtin_amdgcn_cvt_pkrtz(a0[0], a0[1]);
        p[1] = __builtin_amdgcn_cvt_pkrtz(a0[2], a0[3]);
        p[2] = __builtin_amdgcn_cvt_pkrtz(a1[0], a1[1]);
        p[3] = __builtin_amdgcn_cvt_pkrtz(a1[2], a1[3]);
        half8v af;
        __builtin_memcpy(&af, &p[0], 16);
        const int ch = c * 4 + quad;
        #pragma unroll
        for (int nt = 0; nt < 8; ++nt) {
            const int n = l16 * 8 + nt;
            const half8v* pb = (const half8v*)&ldsW[n * 16 + (ch ^ (l16 & 7))];
            acc[nt] = __builtin_amdgcn_mfma_f32_16x16x32_f16(af, *pb, acc[nt], 0, 0, 0);
        }
    }

    float bv[8];
    if (addB) {
        const float4v* pb1 = (const float4v*)(b1 + l16 * 8);
        float4v x0 = pb1[0], x1 = pb1[1];
        bv[0]=x0[0]; bv[1]=x0[1]; bv[2]=x0[2]; bv[3]=x0[3];
        bv[4]=x1[0]; bv[5]=x1[1]; bv[6]=x1[2]; bv[7]=x1[3];
    } else {
        #pragma unroll
        for (int i = 0; i < 8; ++i) bv[i] = 0.0f;
    }

    const int rbase = m0 + wave * 16 + quad * 4;
    #pragma unroll
    for (int r = 0; r < 4; ++r) {
        int rr2 = rbase + r;
        if (rr2 < M) {
            half8v o;
            #pragma unroll
            for (int nt = 0; nt < 8; ++nt) o[nt] = (_Float16)(acc[nt][r] + bv[nt]);
            *(half8v*)&U[(long)rr2 * 128 + l16 * 8] = o;
        }
    }
}

// ---- K4: one WG per bucket; u_s window in LDS (swizzled); gather u_c only ----
__global__ __launch_bounds__(512) void k4_edge(
    const uint2* __restrict__ perm, const unsigned* __restrict__ bucketStart,
    const _Float16* __restrict__ us, const _Float16* __restrict__ uc,
    const _Float16* __restrict__ w2h, const float* __restrict__ b2,
    float* __restrict__ out, int Ms)
{
    __shared__ uint4 lu[4096];          // 256 rows x 16 chunks (64 KB), swizzled
    const int t = threadIdx.x, b = blockIdx.x;
    const int r0 = b << 8;
    const uint4* usv = (const uint4*)us;
    #pragma unroll
    for (int i = 0; i < 8; ++i) {
        int j = t + i * 512;            // 4096 uint4: rowloc=j>>4, ch=j&15
        int rl = j >> 4, ch = j & 15;
        int r = r0 + rl; if (r >= Ms) r = Ms - 1;
        lu[rl * 16 + (ch ^ (rl & 15))] = usv[(long)r * 16 + ch];
    }
    const int sub = t & 7;
    const uint4* pw = ((const uint4*)w2h) + sub * 2;
    uint4 w0 = pw[0], w1 = pw[1];
    half2v W[8];
    *(uint4*)&W[0] = w0; *(uint4*)&W[4] = w1;
    const float b2v = b2[0];
    const half2v zero = {(_Float16)0, (_Float16)0};
    unsigned s0 = bucketStart[b], s1 = bucketStart[b + 1];
    __syncthreads();

    for (unsigned e = s0 + (t >> 3); e < s1; e += 64) {
        uint2 pc = perm[e];
        unsigned rloc = pc.x >> 15, cc = pc.x & 32767u;
        int m = rloc & 15;
        uint4 a0 = lu[rloc * 16 + ((sub * 2) ^ m)];
        uint4 a1 = lu[rloc * 16 + ((sub * 2 + 1) ^ m)];
        const uint4* pb = ((const uint4*)uc) + (long)cc * 16 + sub * 2;
        uint4 u0 = pb[0], u1 = pb[1];

        half2v A[8], B[8];
        *(uint4*)&A[0] = a0; *(uint4*)&A[4] = a1;
        *(uint4*)&B[0] = u0; *(uint4*)&B[4] = u1;

        float s = 0.0f;
        #pragma unroll
        for (int i = 0; i < 8; ++i) {
            half2v h = A[i] + B[i];                   // v_pk_add_f16
            h = __builtin_elementwise_max(h, zero);   // v_pk_max_f16
            s += (float)h[0] * (float)W[i][0];        // v_fma_mix
            s += (float)h[1] * (float)W[i][1];
        }
        s += __shfl_xor(s, 1);
        s += __shfl_xor(s, 2);
        s += __shfl_xor(s, 4);
        if (sub == 0) out[pc.y] = s + b2v;
    }
}

extern "C" void kernel_launch(void* const* d_in, const int* in_sizes, int n_in,
                              void* d_out, int out_size, void* d_ws, size_t ws_size,
                              hipStream_t stream) {
    const float* zs  = (const float*)d_in[0];
    const float* zc  = (const float*)d_in[1];
    const int*   row = (const int*)d_in[2];
    const int*   col = (const int*)d_in[3];
    const float* W1  = (const float*)d_in[4];
    const float* b1  = (const float*)d_in[5];
    const float* W2  = (const float*)d_in[6];
    const float* b2  = (const float*)d_in[7];
    float* out = (float*)d_out;

    const int Ms = in_sizes[0] / 128;   // 100000
    const int Mc = in_sizes[1] / 128;   // 20000
    const int E  = in_sizes[2];         // 1000000

    char* w = (char*)d_ws;
    _Float16* Wt     = (_Float16*)(w);                  //      0 .. 65536
    _Float16* w2h    = (_Float16*)(w + 65536);          //  65536 .. 65792
    unsigned* bstart = (unsigned*)(w + 66048);          //  (NB+1)*4 = 2052
    unsigned* cursor = (unsigned*)(w + 69632);          //  2048
    unsigned* part   = (unsigned*)(w + 73728);          //  nbh*NB*4
    const int nbh = (E + EBLK_H - 1) / EBLK_H;          //  123 -> 251,904 B
    const int nbss = (E + EBLK_S - 1) / EBLK_S;         //  489
    size_t off = 73728 + (size_t)nbh * NB * 4;
    off = (off + 4095) & ~(size_t)4095;
    _Float16* us = (_Float16*)(w + off);                //  Ms*256 B
    _Float16* uc = (_Float16*)(w + off + (size_t)Ms * 256);
    uint2* perm  = (uint2*)(w + off + (size_t)(Ms + Mc) * 256);   // E*8 B

    const int nbs = (Ms + 63) / 64, nbc = (Mc + 63) / 64;
    const int nbuckets = (Ms + 255) >> 8;               // 391

    k1_conv_hist<<<9 + nbh, 256, 0, stream>>>(W1, W2, row, Wt, w2h, part, E);
    k2_scan<<<1, 512, 0, stream>>>(part, bstart, cursor, nbh, E);
    k3_scatter_gemm<<<nbss + nbs + nbc, 256, 0, stream>>>(row, col, cursor, perm, E, nbss,
                                                          zs, zc, Wt, b1, us, uc, Ms, Mc, nbs);
    k4_edge<<<nbuckets, 512, 0, stream>>>(perm, bstart, us, uc, w2h, b2, out, Ms);
}

// Round 6
// 191.944 us; speedup vs baseline: 1.1313x; 1.1313x over previous
//
#include <hip/hip_runtime.h>
#include <hip/hip_bf16.h>
#include <hip/hip_fp16.h>

// out[e] = relu(z_s[row[e]]@W1_top + z_c[col[e]]@W1_bot + b1) @ W2 + b2
// u_s = z_s@W1_top + b1 (f16), u_c = z_c@W1_bot (f16) in ws.
// Edges counting-sorted by row>>7 (782 buckets, 128 rows = 32KB f16 window).
// k4: one WG/bucket, u_s window in LDS (XOR swizzle), pipelined perm/uc gather.
// Launches: memset(hist) | k1 conv+hist | k2 scan | k3 scatter||gemm | k4 edge.

typedef _Float16 half2v __attribute__((ext_vector_type(2)));
typedef _Float16 half8v __attribute__((ext_vector_type(8)));
typedef __fp16   fp16x2 __attribute__((ext_vector_type(2)));
typedef float    float4v __attribute__((ext_vector_type(4)));

#define NB 1024         // bins (buckets 0..781 used)
#define EH 8448         // edges per hist block (33 x 256)
#define EBLK_S 2048     // edges per scatter block

// ---- K1: blocks 0-7 W1->Wt f16 transpose; 8: W2->f16; 9+: hist (atomic) ----
__global__ __launch_bounds__(256) void k1_conv_hist(
    const float* __restrict__ W1, const float* __restrict__ W2,
    const int* __restrict__ row,
    _Float16* __restrict__ Wt, _Float16* __restrict__ w2h,
    unsigned* __restrict__ hist, int E)
{
    int b = blockIdx.x, t = threadIdx.x;
    if (b >= 9) {
        __shared__ unsigned h[NB];
        #pragma unroll
        for (int i = 0; i < 4; ++i) h[t + i * 256] = 0;
        __syncthreads();
        long b0 = (long)(b - 9) * EH;
        for (int i = 0; i < 33; ++i) {
            long e = b0 + i * 256 + t;
            if (e < E) atomicAdd(&h[row[e] >> 7], 1u);
        }
        __syncthreads();
        #pragma unroll
        for (int i = 0; i < 4; ++i) {
            unsigned v = h[t + i * 256];
            if (v) atomicAdd(&hist[t + i * 256], v);
        }
        return;
    }
    if (b == 8) { if (t < 128) w2h[t] = (_Float16)W2[t]; return; }
    __shared__ _Float16 lds[32][136];
    int h2 = b >> 2, n0 = (b & 3) * 32;
    for (int i = 0; i < 16; ++i) {
        int idx = i * 256 + t;
        int k = idx >> 5, nn = idx & 31;
        lds[nn][k] = (_Float16)W1[(h2 * 128 + k) * 128 + n0 + nn];
    }
    __syncthreads();
    for (int j = 0; j < 2; ++j) {
        int idx = j * 256 + t;
        int nn = idx >> 4, kc = idx & 15;
        half8v v;
        #pragma unroll
        for (int q = 0; q < 8; ++q) v[q] = lds[nn][kc * 8 + q];
        *(half8v*)&Wt[((h2 * 128 + n0 + nn) * 128) + kc * 8] = v;
    }
}

// ---- K2: exclusive scan of 1024 bins (tiny) ----
__global__ __launch_bounds__(1024) void k2_scan(const unsigned* __restrict__ hist,
                                                unsigned* __restrict__ bucketStart,
                                                unsigned* __restrict__ cursor, int E)
{
    __shared__ unsigned s[NB];
    int t = threadIdx.x;
    unsigned v = hist[t];
    s[t] = v;
    __syncthreads();
    for (int d = 1; d < NB; d <<= 1) {
        unsigned x = (t >= d) ? s[t - d] : 0u;
        __syncthreads();
        s[t] += x;
        __syncthreads();
    }
    unsigned excl = s[t] - v;
    bucketStart[t] = excl;
    cursor[t] = excl;
    if (t == 0) bucketStart[NB] = (unsigned)E;
}

// ---- K3: blocks [0,nbs_s) scatter; rest fused GEMM (they overlap) ----
__global__ __launch_bounds__(256) void k3_scatter_gemm(
    const int* __restrict__ row, const int* __restrict__ col,
    unsigned* __restrict__ cursor, uint2* __restrict__ perm, int E, int nbs_s,
    const float* __restrict__ Zs, const float* __restrict__ Zc,
    const _Float16* __restrict__ Wt, const float* __restrict__ b1,
    _Float16* __restrict__ Us, _Float16* __restrict__ Uc,
    int Ms, int Mc, int nbs)
{
    const int t = threadIdx.x;
    if (blockIdx.x < (unsigned)nbs_s) {
        __shared__ unsigned h[NB];
        __shared__ unsigned base[NB];
        #pragma unroll
        for (int i = 0; i < 4; ++i) h[t + i * 256] = 0;
        __syncthreads();
        long b0 = (long)blockIdx.x * EBLK_S;
        int sk[8], rr[8], cc[8];
        #pragma unroll
        for (int i = 0; i < 8; ++i) {
            long e = b0 + i * 256 + t;
            if (e < E) {
                rr[i] = row[e]; cc[i] = col[e];
                sk[i] = rr[i] >> 7;
                atomicAdd(&h[sk[i]], 1u);
            } else sk[i] = -1;
        }
        __syncthreads();
        #pragma unroll
        for (int i = 0; i < 4; ++i) {
            unsigned hv = h[t + i * 256];
            if (hv) base[t + i * 256] = atomicAdd(&cursor[t + i * 256], hv);
        }
        __syncthreads();
        #pragma unroll
        for (int i = 0; i < 4; ++i) h[t + i * 256] = 0;
        __syncthreads();
        #pragma unroll
        for (int i = 0; i < 8; ++i) {
            if (sk[i] >= 0) {
                unsigned off = atomicAdd(&h[sk[i]], 1u);
                unsigned pos = base[sk[i]] + off;
                long e = b0 + i * 256 + t;
                perm[pos] = make_uint2(((unsigned)(rr[i] & 127) << 15) | (unsigned)cc[i],
                                       (unsigned)e);
            }
        }
        return;
    }
    // ---------------- GEMM ----------------
    __shared__ uint4 ldsW[2048];
    const int bid = blockIdx.x - nbs_s;

    const float* Z; _Float16* U; const _Float16* W; int M, m0, addB;
    if (bid < nbs) { Z = Zs; U = Us; M = Ms; m0 = bid * 64;         W = Wt;         addB = 1; }
    else           { Z = Zc; U = Uc; M = Mc; m0 = (bid - nbs) * 64; W = Wt + 16384; addB = 0; }

    const uint4* Wv = (const uint4*)W;
    #pragma unroll
    for (int i = 0; i < 8; ++i) {
        int j = i * 256 + t;
        int n = j >> 4, ch = j & 15;
        ldsW[n * 16 + (ch ^ ((n >> 3) & 7))] = Wv[j];
    }
    __syncthreads();

    const int wave = t >> 6, lane = t & 63, quad = lane >> 4, l16 = lane & 15;
    int mrow = m0 + wave * 16 + l16;
    int mload = mrow < M ? mrow : M - 1;
    const float* zrow = Z + (long)mload * 128;

    float4v acc[8];
    #pragma unroll
    for (int nt = 0; nt < 8; ++nt) acc[nt] = (float4v)(0.0f);

    #pragma unroll
    for (int c = 0; c < 4; ++c) {
        const float4v* pa = (const float4v*)(zrow + c * 32 + quad * 8);
        float4v a0 = pa[0], a1 = pa[1];
        fp16x2 p[4];
        p[0] = __builtin_amdgcn_cvt_pkrtz(a0[0], a0[1]);
        p[1] = __builtin_amdgcn_cvt_pkrtz(a0[2], a0[3]);
        p[2] = __builtin_amdgcn_cvt_pkrtz(a1[0], a1[1]);
        p[3] = __builtin_amdgcn_cvt_pkrtz(a1[2], a1[3]);
        half8v af;
        __builtin_memcpy(&af, &p[0], 16);
        const int ch = c * 4 + quad;
        #pragma unroll
        for (int nt = 0; nt < 8; ++nt) {
            const int n = l16 * 8 + nt;
            const half8v* pb = (const half8v*)&ldsW[n * 16 + (ch ^ (l16 & 7))];
            acc[nt] = __builtin_amdgcn_mfma_f32_16x16x32_f16(af, *pb, acc[nt], 0, 0, 0);
        }
    }

    float bv[8];
    if (addB) {
        const float4v* pb1 = (const float4v*)(b1 + l16 * 8);
        float4v x0 = pb1[0], x1 = pb1[1];
        bv[0]=x0[0]; bv[1]=x0[1]; bv[2]=x0[2]; bv[3]=x0[3];
        bv[4]=x1[0]; bv[5]=x1[1]; bv[6]=x1[2]; bv[7]=x1[3];
    } else {
        #pragma unroll
        for (int i = 0; i < 8; ++i) bv[i] = 0.0f;
    }

    const int rbase = m0 + wave * 16 + quad * 4;
    #pragma unroll
    for (int r = 0; r < 4; ++r) {
        int rr2 = rbase + r;
        if (rr2 < M) {
            half8v o;
            #pragma unroll
            for (int nt = 0; nt < 8; ++nt) o[nt] = (_Float16)(acc[nt][r] + bv[nt]);
            *(half8v*)&U[(long)rr2 * 128 + l16 * 8] = o;
        }
    }
}

// ---- K4: one WG per 128-row bucket; u_s window in LDS; pipelined gather ----
__global__ __launch_bounds__(256) void k4_edge(
    const uint2* __restrict__ perm, const unsigned* __restrict__ bucketStart,
    const _Float16* __restrict__ us, const _Float16* __restrict__ uc,
    const _Float16* __restrict__ w2h, const float* __restrict__ b2,
    float* __restrict__ out, int Ms)
{
    __shared__ uint4 lu[2048];          // 128 rows x 16 chunks (32 KB), swizzled
    const int t = threadIdx.x, b = blockIdx.x;
    const int r0 = b << 7;
    const uint4* usv = (const uint4*)us;
    #pragma unroll
    for (int i = 0; i < 8; ++i) {
        int j = t + i * 256;            // 2048 uint4
        int rl = j >> 4, ch = j & 15;
        int r = r0 + rl; if (r >= Ms) r = Ms - 1;
        lu[rl * 16 + (ch ^ (rl & 15))] = usv[(long)r * 16 + ch];
    }
    const int sub = t & 7;
    const uint4* pw = ((const uint4*)w2h) + sub * 2;
    uint4 w0 = pw[0], w1 = pw[1];
    half2v W[8];
    *(uint4*)&W[0] = w0; *(uint4*)&W[4] = w1;
    const float b2v = b2[0];
    const half2v zero = {(_Float16)0, (_Float16)0};
    unsigned s0 = bucketStart[b], s1 = bucketStart[b + 1];
    __syncthreads();

    if (s0 >= s1) return;
    const unsigned cnt = s1 - s0;
    const uint4* ucv = (const uint4*)uc;

    // 2-deep perm / 1-deep uc software pipeline (clamped prefetch indices)
    unsigned k = t >> 3;                                 // slot 0..31, stride 32
    uint2 pcA = perm[s0 + (k       < cnt ? k       : 0u)];
    uint2 pcB = perm[s0 + (k + 32u < cnt ? k + 32u : 0u)];
    uint4 U0, U1;
    {
        const uint4* pb = ucv + (long)(pcA.x & 32767u) * 16 + sub * 2;
        U0 = pb[0]; U1 = pb[1];
    }
    for (; k < cnt; k += 32u) {
        uint2 pcC = perm[s0 + (k + 64u < cnt ? k + 64u : 0u)];
        uint4 V0, V1;
        {
            const uint4* pb = ucv + (long)(pcB.x & 32767u) * 16 + sub * 2;
            V0 = pb[0]; V1 = pb[1];
        }
        unsigned rloc = pcA.x >> 15;
        int m = rloc & 15;
        uint4 a0 = lu[rloc * 16 + ((sub * 2) ^ m)];
        uint4 a1 = lu[rloc * 16 + ((sub * 2 + 1) ^ m)];

        half2v A[8], B[8];
        *(uint4*)&A[0] = a0; *(uint4*)&A[4] = a1;
        *(uint4*)&B[0] = U0; *(uint4*)&B[4] = U1;

        float s = 0.0f;
        #pragma unroll
        for (int i = 0; i < 8; ++i) {
            half2v h = A[i] + B[i];                   // v_pk_add_f16
            h = __builtin_elementwise_max(h, zero);   // v_pk_max_f16
            s += (float)h[0] * (float)W[i][0];
            s += (float)h[1] * (float)W[i][1];
        }
        s += __shfl_xor(s, 1);
        s += __shfl_xor(s, 2);
        s += __shfl_xor(s, 4);
        if (sub == 0) out[pcA.y] = s + b2v;

        pcA = pcB; pcB = pcC; U0 = V0; U1 = V1;
    }
}

extern "C" void kernel_launch(void* const* d_in, const int* in_sizes, int n_in,
                              void* d_out, int out_size, void* d_ws, size_t ws_size,
                              hipStream_t stream) {
    const float* zs  = (const float*)d_in[0];
    const float* zc  = (const float*)d_in[1];
    const int*   row = (const int*)d_in[2];
    const int*   col = (const int*)d_in[3];
    const float* W1  = (const float*)d_in[4];
    const float* b1  = (const float*)d_in[5];
    const float* W2  = (const float*)d_in[6];
    const float* b2  = (const float*)d_in[7];
    float* out = (float*)d_out;

    const int Ms = in_sizes[0] / 128;   // 100000
    const int Mc = in_sizes[1] / 128;   // 20000
    const int E  = in_sizes[2];         // 1000000

    char* w = (char*)d_ws;
    _Float16* Wt     = (_Float16*)(w);                  //      0 .. 65536
    _Float16* w2h    = (_Float16*)(w + 65536);          //  256 B
    unsigned* hist   = (unsigned*)(w + 66560);          //  4096 B
    unsigned* bstart = (unsigned*)(w + 70656);          //  (NB+1)*4 = 4100 B
    unsigned* cursor = (unsigned*)(w + 75776);          //  4096 B
    _Float16* us     = (_Float16*)(w + 81920);          //  Ms*256 B
    _Float16* uc     = (_Float16*)(w + 81920 + (size_t)Ms * 256);
    uint2*    perm   = (uint2*)(w + 81920 + (size_t)(Ms + Mc) * 256);  // E*8 B

    const int nbs = (Ms + 63) / 64, nbc = (Mc + 63) / 64;
    const int nbh = (E + EH - 1) / EH;                  // 119
    const int nbss = (E + EBLK_S - 1) / EBLK_S;         // 489
    const int nbuckets = (Ms + 127) >> 7;               // 782

    hipMemsetAsync(hist, 0, NB * 4, stream);
    k1_conv_hist<<<9 + nbh, 256, 0, stream>>>(W1, W2, row, Wt, w2h, hist, E);
    k2_scan<<<1, 1024, 0, stream>>>(hist, bstart, cursor, E);
    k3_scatter_gemm<<<nbss + nbs + nbc, 256, 0, stream>>>(row, col, cursor, perm, E, nbss,
                                                          zs, zc, Wt, b1, us, uc, Ms, Mc, nbs);
    k4_edge<<<nbuckets, 256, 0, stream>>>(perm, bstart, us, uc, w2h, b2, out, Ms);
}

// Round 7
// 178.285 us; speedup vs baseline: 1.2180x; 1.0766x over previous
//
#include <hip/hip_runtime.h>
#include <hip/hip_bf16.h>
#include <hip/hip_fp16.h>

// out[e] = relu(z_s[row[e]]@W1_top + z_c[col[e]]@W1_bot + b1) @ W2 + b2
// u_s = z_s@W1_top + b1 (f16), u_c = z_c@W1_bot (f16) in ws.
// Edges counting-sorted by row>>7 (782 buckets, 128 rows = 32KB f16 window).
// k4: 2 WGs/bucket, u_s window in LDS (XOR swizzle), pipelined perm/uc gather.
// k3: scatter blocks + gemm blocks in one grid (overlap); gemm does 4 M-tiles
// per block with register prefetch of next tile's Z; LDS unioned (32 KB).

typedef _Float16 half2v __attribute__((ext_vector_type(2)));
typedef _Float16 half8v __attribute__((ext_vector_type(8)));
typedef __fp16   fp16x2 __attribute__((ext_vector_type(2)));
typedef float    float4v __attribute__((ext_vector_type(4)));

#define NB 1024         // bins (buckets 0..781 used)
#define EH 8448         // edges per hist block (33 x 256)
#define EBLK_S 4096     // edges per scatter block
#define TPB 4           // M-tiles (64 rows) per gemm block

// ---- K1: blocks 0-7 W1->Wt f16 transpose; 8: W2->f16; 9+: hist (atomic) ----
__global__ __launch_bounds__(256) void k1_conv_hist(
    const float* __restrict__ W1, const float* __restrict__ W2,
    const int* __restrict__ row,
    _Float16* __restrict__ Wt, _Float16* __restrict__ w2h,
    unsigned* __restrict__ hist, int E)
{
    int b = blockIdx.x, t = threadIdx.x;
    if (b >= 9) {
        __shared__ unsigned h[NB];
        #pragma unroll
        for (int i = 0; i < 4; ++i) h[t + i * 256] = 0;
        __syncthreads();
        long b0 = (long)(b - 9) * EH;
        for (int i = 0; i < 33; ++i) {
            long e = b0 + i * 256 + t;
            if (e < E) atomicAdd(&h[row[e] >> 7], 1u);
        }
        __syncthreads();
        #pragma unroll
        for (int i = 0; i < 4; ++i) {
            unsigned v = h[t + i * 256];
            if (v) atomicAdd(&hist[t + i * 256], v);
        }
        return;
    }
    if (b == 8) { if (t < 128) w2h[t] = (_Float16)W2[t]; return; }
    __shared__ _Float16 lds[32][136];
    int h2 = b >> 2, n0 = (b & 3) * 32;
    for (int i = 0; i < 16; ++i) {
        int idx = i * 256 + t;
        int k = idx >> 5, nn = idx & 31;
        lds[nn][k] = (_Float16)W1[(h2 * 128 + k) * 128 + n0 + nn];
    }
    __syncthreads();
    for (int j = 0; j < 2; ++j) {
        int idx = j * 256 + t;
        int nn = idx >> 4, kc = idx & 15;
        half8v v;
        #pragma unroll
        for (int q = 0; q < 8; ++q) v[q] = lds[nn][kc * 8 + q];
        *(half8v*)&Wt[((h2 * 128 + n0 + nn) * 128) + kc * 8] = v;
    }
}

// ---- K2: exclusive scan of 1024 bins ----
__global__ __launch_bounds__(1024) void k2_scan(const unsigned* __restrict__ hist,
                                                unsigned* __restrict__ bucketStart,
                                                unsigned* __restrict__ cursor, int E)
{
    __shared__ unsigned s[NB];
    int t = threadIdx.x;
    unsigned v = hist[t];
    s[t] = v;
    __syncthreads();
    for (int d = 1; d < NB; d <<= 1) {
        unsigned x = (t >= d) ? s[t - d] : 0u;
        __syncthreads();
        s[t] += x;
        __syncthreads();
    }
    unsigned excl = s[t] - v;
    bucketStart[t] = excl;
    cursor[t] = excl;
    if (t == 0) bucketStart[NB] = (unsigned)E;
}

// ---- K3: blocks [0,nbs_s) scatter; rest = gemm, 4 tiles/block, prefetch ----
__global__ __launch_bounds__(256, 3) void k3_scatter_gemm(
    const int* __restrict__ row, const int* __restrict__ col,
    unsigned* __restrict__ cursor, uint2* __restrict__ perm, int E, int nbs_s,
    const float* __restrict__ Zs, const float* __restrict__ Zc,
    const _Float16* __restrict__ Wt, const float* __restrict__ b1,
    _Float16* __restrict__ Us, _Float16* __restrict__ Uc,
    int Ms, int Mc, int nbsg)
{
    __shared__ __align__(16) unsigned smem[8192];   // 32 KB, unioned
    const int t = threadIdx.x;
    if (blockIdx.x < (unsigned)nbs_s) {
        // ---------------- scatter ----------------
        unsigned* h    = smem;          // [NB]
        unsigned* base = smem + NB;     // [NB]
        #pragma unroll
        for (int i = 0; i < 4; ++i) h[t + i * 256] = 0;
        __syncthreads();
        long b0 = (long)blockIdx.x * EBLK_S;
        int sk[16], rr[16], cc[16];
        #pragma unroll
        for (int i = 0; i < 16; ++i) {
            long e = b0 + i * 256 + t;
            if (e < E) {
                rr[i] = row[e]; cc[i] = col[e];
                sk[i] = rr[i] >> 7;
                atomicAdd(&h[sk[i]], 1u);
            } else sk[i] = -1;
        }
        __syncthreads();
        #pragma unroll
        for (int i = 0; i < 4; ++i) {
            unsigned hv = h[t + i * 256];
            if (hv) base[t + i * 256] = atomicAdd(&cursor[t + i * 256], hv);
        }
        __syncthreads();
        #pragma unroll
        for (int i = 0; i < 4; ++i) h[t + i * 256] = 0;
        __syncthreads();
        #pragma unroll
        for (int i = 0; i < 16; ++i) {
            if (sk[i] >= 0) {
                unsigned off = atomicAdd(&h[sk[i]], 1u);
                unsigned pos = base[sk[i]] + off;
                long e = b0 + i * 256 + t;
                perm[pos] = make_uint2(((unsigned)(rr[i] & 127) << 15) | (unsigned)cc[i],
                                       (unsigned)e);
            }
        }
        return;
    }
    // ---------------- GEMM: TPB tiles of 64 rows ----------------
    uint4* ldsW = (uint4*)smem;
    int gid = blockIdx.x - nbs_s;

    const float* Z; _Float16* U; const _Float16* W; int M, tbase, addB;
    if (gid < nbsg) { Z = Zs; U = Us; M = Ms; W = Wt;         addB = 1; tbase = gid * TPB; }
    else { gid -= nbsg; Z = Zc; U = Uc; M = Mc; W = Wt + 16384; addB = 0; tbase = gid * TPB; }

    const uint4* Wv = (const uint4*)W;
    #pragma unroll
    for (int i = 0; i < 8; ++i) {
        int j = i * 256 + t;
        int n = j >> 4, ch = j & 15;
        ldsW[n * 16 + (ch ^ ((n >> 3) & 7))] = Wv[j];
    }
    __syncthreads();

    const int wave = t >> 6, lane = t & 63, quad = lane >> 4, l16 = lane & 15;

    float bv[8];
    if (addB) {
        const float4v* pb1 = (const float4v*)(b1 + l16 * 8);
        float4v x0 = pb1[0], x1 = pb1[1];
        bv[0]=x0[0]; bv[1]=x0[1]; bv[2]=x0[2]; bv[3]=x0[3];
        bv[4]=x1[0]; bv[5]=x1[1]; bv[6]=x1[2]; bv[7]=x1[3];
    } else {
        #pragma unroll
        for (int i = 0; i < 8; ++i) bv[i] = 0.0f;
    }

    float4v buf[2][8];
    // load lane's Z slice for tile `tile` into dst: 2 float4s per K-chunk c
    #define LOADZ(dst, tile) do {                                              \
        int mrow_ = (tile) * 64 + wave * 16 + l16;                             \
        int mload_ = mrow_ < M ? mrow_ : M - 1;                                \
        const float4v* p_ = (const float4v*)(Z + (long)mload_ * 128);          \
        _Pragma("unroll")                                                      \
        for (int c_ = 0; c_ < 4; ++c_) {                                       \
            (dst)[2*c_]   = p_[c_*8 + quad*2];                                 \
            (dst)[2*c_+1] = p_[c_*8 + quad*2 + 1];                             \
        }                                                                      \
    } while (0)

    LOADZ(buf[0], tbase);
    #pragma unroll
    for (int tt = 0; tt < TPB; ++tt) {
        const float4v* cur = buf[tt & 1];
        if (tt + 1 < TPB) LOADZ(buf[(tt + 1) & 1], tbase + tt + 1);

        float4v acc[8];
        #pragma unroll
        for (int nt = 0; nt < 8; ++nt) acc[nt] = (float4v)(0.0f);

        #pragma unroll
        for (int c = 0; c < 4; ++c) {
            float4v a0 = cur[2*c], a1 = cur[2*c+1];
            fp16x2 p[4];
            p[0] = __builtin_amdgcn_cvt_pkrtz(a0[0], a0[1]);
            p[1] = __builtin_amdgcn_cvt_pkrtz(a0[2], a0[3]);
            p[2] = __builtin_amdgcn_cvt_pkrtz(a1[0], a1[1]);
            p[3] = __builtin_amdgcn_cvt_pkrtz(a1[2], a1[3]);
            half8v af;
            __builtin_memcpy(&af, &p[0], 16);
            const int ch = c * 4 + quad;
            #pragma unroll
            for (int nt = 0; nt < 8; ++nt) {
                const int n = l16 * 8 + nt;
                const half8v* pb = (const half8v*)&ldsW[n * 16 + (ch ^ (l16 & 7))];
                acc[nt] = __builtin_amdgcn_mfma_f32_16x16x32_f16(af, *pb, acc[nt], 0, 0, 0);
            }
        }

        const int rbase = (tbase + tt) * 64 + wave * 16 + quad * 4;
        #pragma unroll
        for (int r = 0; r < 4; ++r) {
            int rr2 = rbase + r;
            if (rr2 < M) {
                half8v o;
                #pragma unroll
                for (int nt = 0; nt < 8; ++nt) o[nt] = (_Float16)(acc[nt][r] + bv[nt]);
                *(half8v*)&U[(long)rr2 * 128 + l16 * 8] = o;
            }
        }
    }
    #undef LOADZ
}

// ---- K4: 2 WGs per 128-row bucket; u_s window in LDS; pipelined gather ----
__global__ __launch_bounds__(256) void k4_edge(
    const uint2* __restrict__ perm, const unsigned* __restrict__ bucketStart,
    const _Float16* __restrict__ us, const _Float16* __restrict__ uc,
    const _Float16* __restrict__ w2h, const float* __restrict__ b2,
    float* __restrict__ out, int Ms)
{
    __shared__ uint4 lu[2048];          // 128 rows x 16 chunks (32 KB), swizzled
    const int t = threadIdx.x;
    const int b = blockIdx.x >> 1, half = blockIdx.x & 1;
    const int r0 = b << 7;
    const uint4* usv = (const uint4*)us;
    #pragma unroll
    for (int i = 0; i < 8; ++i) {
        int j = t + i * 256;            // 2048 uint4
        int rl = j >> 4, ch = j & 15;
        int r = r0 + rl; if (r >= Ms) r = Ms - 1;
        lu[rl * 16 + (ch ^ (rl & 15))] = usv[(long)r * 16 + ch];
    }
    const int sub = t & 7;
    const uint4* pw = ((const uint4*)w2h) + sub * 2;
    uint4 w0 = pw[0], w1 = pw[1];
    half2v W[8];
    *(uint4*)&W[0] = w0; *(uint4*)&W[4] = w1;
    const float b2v = b2[0];
    const half2v zero = {(_Float16)0, (_Float16)0};
    unsigned s0b = bucketStart[b], s1b = bucketStart[b + 1];
    __syncthreads();

    unsigned cntAll = s1b - s0b;
    if (cntAll == 0) return;
    unsigned hc = (cntAll + 1) >> 1;
    unsigned s0 = s0b + half * hc;
    unsigned s1 = s0 + hc; if (s1 > s1b) s1 = s1b;
    if (s0 >= s1) return;
    const unsigned cnt = s1 - s0;
    const uint4* ucv = (const uint4*)uc;

    // 2-deep perm / 1-deep uc software pipeline (clamped prefetch indices)
    unsigned k = t >> 3;                                 // slot 0..31, stride 32
    uint2 pcA = perm[s0 + (k       < cnt ? k       : 0u)];
    uint2 pcB = perm[s0 + (k + 32u < cnt ? k + 32u : 0u)];
    uint4 U0, U1;
    {
        const uint4* pb = ucv + (long)(pcA.x & 32767u) * 16 + sub * 2;
        U0 = pb[0]; U1 = pb[1];
    }
    for (; k < cnt; k += 32u) {
        uint2 pcC = perm[s0 + (k + 64u < cnt ? k + 64u : 0u)];
        uint4 V0, V1;
        {
            const uint4* pb = ucv + (long)(pcB.x & 32767u) * 16 + sub * 2;
            V0 = pb[0]; V1 = pb[1];
        }
        unsigned rloc = pcA.x >> 15;
        int m = rloc & 15;
        uint4 a0 = lu[rloc * 16 + ((sub * 2) ^ m)];
        uint4 a1 = lu[rloc * 16 + ((sub * 2 + 1) ^ m)];

        half2v A[8], B[8];
        *(uint4*)&A[0] = a0; *(uint4*)&A[4] = a1;
        *(uint4*)&B[0] = U0; *(uint4*)&B[4] = U1;

        float s = 0.0f;
        #pragma unroll
        for (int i = 0; i < 8; ++i) {
            half2v h = A[i] + B[i];                   // v_pk_add_f16
            h = __builtin_elementwise_max(h, zero);   // v_pk_max_f16
            s += (float)h[0] * (float)W[i][0];
            s += (float)h[1] * (float)W[i][1];
        }
        s += __shfl_xor(s, 1);
        s += __shfl_xor(s, 2);
        s += __shfl_xor(s, 4);
        if (sub == 0) out[pcA.y] = s + b2v;

        pcA = pcB; pcB = pcC; U0 = V0; U1 = V1;
    }
}

extern "C" void kernel_launch(void* const* d_in, const int* in_sizes, int n_in,
                              void* d_out, int out_size, void* d_ws, size_t ws_size,
                              hipStream_t stream) {
    const float* zs  = (const float*)d_in[0];
    const float* zc  = (const float*)d_in[1];
    const int*   row = (const int*)d_in[2];
    const int*   col = (const int*)d_in[3];
    const float* W1  = (const float*)d_in[4];
    const float* b1  = (const float*)d_in[5];
    const float* W2  = (const float*)d_in[6];
    const float* b2  = (const float*)d_in[7];
    float* out = (float*)d_out;

    const int Ms = in_sizes[0] / 128;   // 100000
    const int Mc = in_sizes[1] / 128;   // 20000
    const int E  = in_sizes[2];         // 1000000

    char* w = (char*)d_ws;
    _Float16* Wt     = (_Float16*)(w);                  //      0 .. 65536
    _Float16* w2h    = (_Float16*)(w + 65536);          //  256 B
    unsigned* hist   = (unsigned*)(w + 66560);          //  4096 B
    unsigned* bstart = (unsigned*)(w + 70656);          //  (NB+1)*4 = 4100 B
    unsigned* cursor = (unsigned*)(w + 75776);          //  4096 B
    _Float16* us     = (_Float16*)(w + 81920);          //  Ms*256 B
    _Float16* uc     = (_Float16*)(w + 81920 + (size_t)Ms * 256);
    uint2*    perm   = (uint2*)(w + 81920 + (size_t)(Ms + Mc) * 256);  // E*8 B

    const int nbs = (Ms + 63) / 64, nbc = (Mc + 63) / 64;      // 1563, 313
    const int nbsg = (nbs + TPB - 1) / TPB;                    // 391
    const int nbcg = (nbc + TPB - 1) / TPB;                    // 79
    const int nbh = (E + EH - 1) / EH;                         // 119
    const int nbss = (E + EBLK_S - 1) / EBLK_S;                // 245
    const int nbuckets = (Ms + 127) >> 7;                      // 782

    hipMemsetAsync(hist, 0, NB * 4, stream);
    k1_conv_hist<<<9 + nbh, 256, 0, stream>>>(W1, W2, row, Wt, w2h, hist, E);
    k2_scan<<<1, 1024, 0, stream>>>(hist, bstart, cursor, E);
    k3_scatter_gemm<<<nbss + nbsg + nbcg, 256, 0, stream>>>(row, col, cursor, perm, E, nbss,
                                                            zs, zc, Wt, b1, us, uc, Ms, Mc, nbsg);
    k4_edge<<<2 * nbuckets, 256, 0, stream>>>(perm, bstart, us, uc, w2h, b2, out, Ms);
}